// Round 12
// baseline (210.329 us; speedup 1.0000x reference)
//
#include <hip/hip_runtime.h>
#include <hip/hip_bf16.h>

#define N_ROWS 8192
#define D_DIM  512
#define NSTEPS 8    // K-steps of BK=64

typedef __attribute__((ext_vector_type(4))) int   i32x4;
typedef __attribute__((ext_vector_type(8))) int   i32x8;
typedef __attribute__((ext_vector_type(16))) float f32x16;

// One wave per row-index i: L2-normalize cxr_i and ehr_i, write fp8 e4m3,
// and compute diag_i = dot(cxr_i,ehr_i)*ia*ib/temp (full fp32) in one pass.
__global__ void normdiag_kernel(const float* __restrict__ cxr, const float* __restrict__ ehr,
                                unsigned char* __restrict__ Ab, unsigned char* __restrict__ Bb,
                                const float* __restrict__ temp, float* __restrict__ dg) {
    const int row = blockIdx.x * 4 + (threadIdx.x >> 6);
    const int lane = threadIdx.x & 63;
    const float4* a4 = (const float4*)(cxr + (size_t)row * D_DIM + lane * 8);
    const float4* b4 = (const float4*)(ehr + (size_t)row * D_DIM + lane * 8);
    float4 a0 = a4[0], a1 = a4[1];
    float4 b0 = b4[0], b1 = b4[1];
    float sa = a0.x*a0.x + a0.y*a0.y + a0.z*a0.z + a0.w*a0.w
             + a1.x*a1.x + a1.y*a1.y + a1.z*a1.z + a1.w*a1.w;
    float sb = b0.x*b0.x + b0.y*b0.y + b0.z*b0.z + b0.w*b0.w
             + b1.x*b1.x + b1.y*b1.y + b1.z*b1.z + b1.w*b1.w;
    float dt = a0.x*b0.x + a0.y*b0.y + a0.z*b0.z + a0.w*b0.w
             + a1.x*b1.x + a1.y*b1.y + a1.z*b1.z + a1.w*b1.w;
#pragma unroll
    for (int s = 1; s < 64; s <<= 1) {
        sa += __shfl_xor(sa, s);
        sb += __shfl_xor(sb, s);
        dt += __shfl_xor(dt, s);
    }
    const float ia = 1.0f / sqrtf(fmaxf(sa, 1e-16f));
    const float ib = 1.0f / sqrtf(fmaxf(sb, 1e-16f));
    if (lane == 0) dg[row] = dt * ia * ib / temp[0];
    float va[8] = {a0.x, a0.y, a0.z, a0.w, a1.x, a1.y, a1.z, a1.w};
    float vb[8] = {b0.x, b0.y, b0.z, b0.w, b1.x, b1.y, b1.z, b1.w};
    int aw0 = __builtin_amdgcn_cvt_pk_fp8_f32(va[0]*ia, va[1]*ia, 0, false);
    aw0     = __builtin_amdgcn_cvt_pk_fp8_f32(va[2]*ia, va[3]*ia, aw0, true);
    int aw1 = __builtin_amdgcn_cvt_pk_fp8_f32(va[4]*ia, va[5]*ia, 0, false);
    aw1     = __builtin_amdgcn_cvt_pk_fp8_f32(va[6]*ia, va[7]*ia, aw1, true);
    int bw0 = __builtin_amdgcn_cvt_pk_fp8_f32(vb[0]*ib, vb[1]*ib, 0, false);
    bw0     = __builtin_amdgcn_cvt_pk_fp8_f32(vb[2]*ib, vb[3]*ib, bw0, true);
    int bw1 = __builtin_amdgcn_cvt_pk_fp8_f32(vb[4]*ib, vb[5]*ib, 0, false);
    bw1     = __builtin_amdgcn_cvt_pk_fp8_f32(vb[6]*ib, vb[7]*ib, bw1, true);
    *(int2*)(Ab + (size_t)row * D_DIM + lane * 8) = make_int2(aw0, aw1);
    *(int2*)(Bb + (size_t)row * D_DIM + lane * 8) = make_int2(bw0, bw1);
}

// by-value 32-byte fragment load: lo/hi i32x4 loads + constructor (the r10
// no-scratch idiom; r11's address-cast writes into i32x8 halves caused alloca
// -> 368 MB scratch spill)
static __device__ __forceinline__ i32x8 ld32(const unsigned char* p) {
    i32x4 lo = *(const i32x4*)p;
    i32x4 hi = *(const i32x4*)(p + 16);
    return (i32x8){lo[0], lo[1], lo[2], lo[3], hi[0], hi[1], hi[2], hi[3]};
}

// fp8 128x128 GEMM, ZERO LDS operands, ZERO K-loop barriers: fragments loaded
// global->VGPR, double-buffered one K-step ahead; 4 independent waves (2x2,
// wave tile 64x64, acc[2][2] f32x16 = 64 regs). 3 blocks/CU (bounds(256,3),
// cap ~170) -> 12 independent wave-streams/CU hide load latency.
// Epilogue: exp((cos-1)/T), diag zeroed, row/col sums -> global atomics.
__global__ __launch_bounds__(256, 3) void gemm_lse_kernel(
        const unsigned char* __restrict__ A, const unsigned char* __restrict__ B,
        const float* __restrict__ temp,
        float* __restrict__ row_sum, float* __restrict__ col_sum) {
    __shared__ float rs_l[128];
    __shared__ float cs_l[128];

    const int tid = threadIdx.x;
    const int lane = tid & 63;
    const int wid = tid >> 6;                 // 4 waves
    const int bm = blockIdx.x & 63;           // bm-major: consecutive blocks
    const int bn = blockIdx.x >> 6;           // share the B panel in L2
    const int wm = wid >> 1, wn = wid & 1;    // wave tile 64x64

    if (tid < 128) rs_l[tid] = 0.f;
    else           cs_l[tid - 128] = 0.f;

    const int c31 = lane & 31, h2 = lane >> 5;

    // operand row pointers (fp8, row stride 512 B); lane covers row base+c31,
    // bytes [h2*32, h2*32+32) of each 64-byte K-step (layout validated r7-r10)
    const unsigned char* rA0 = A + (size_t)(bm * 128 + wm * 64 + c31) * D_DIM + h2 * 32;
    const unsigned char* rA1 = rA0 + 32 * D_DIM;
    const unsigned char* rB0 = B + (size_t)(bn * 128 + wn * 64 + c31) * D_DIM + h2 * 32;
    const unsigned char* rB1 = rB0 + 32 * D_DIM;

    i32x8 Af[2][2], Bf[2][2];
    f32x16 acc[2][2] = {};
    const int sc = 0x7F7F7F7F;   // E8M0 127 -> scale 1.0 for any opsel

    // prologue: fragments for step 0
    Af[0][0] = ld32(rA0); Af[0][1] = ld32(rA1);
    Bf[0][0] = ld32(rB0); Bf[0][1] = ld32(rB1);

#pragma unroll
    for (int s = 0; s < NSTEPS; ++s) {
        const int cb = s & 1, nb = cb ^ 1;
        if (s + 1 < NSTEPS) {
            const int k0 = (s + 1) * 64;
            Af[nb][0] = ld32(rA0 + k0); Af[nb][1] = ld32(rA1 + k0);
            Bf[nb][0] = ld32(rB0 + k0); Bf[nb][1] = ld32(rB1 + k0);
        }
#pragma unroll
        for (int mi = 0; mi < 2; ++mi)
#pragma unroll
            for (int ni = 0; ni < 2; ++ni)
                acc[mi][ni] = __builtin_amdgcn_mfma_scale_f32_32x32x64_f8f6f4(
                    Af[cb][mi], Bf[cb][ni], acc[mi][ni], 0, 0, 0, sc, 0, sc);
    }

    // ---- epilogue: exp + masked diag + row/col reduction ----
    // C/D 32x32 layout: col = lane&31, row = (reg&3) + 8*(reg>>2) + 4*(lane>>5)
    const float invT = 1.0f / temp[0];
    const bool diagBlk = (bm == bn);
    float colpart[2] = {0.f, 0.f};

#pragma unroll
    for (int mi = 0; mi < 2; ++mi) {
        float rowpart[16];
#pragma unroll
        for (int r = 0; r < 16; ++r) rowpart[r] = 0.f;
#pragma unroll
        for (int ni = 0; ni < 2; ++ni) {
            f32x16 a = acc[mi][ni];
#pragma unroll
            for (int r = 0; r < 16; ++r) {
                float e = __expf((a[r] - 1.0f) * invT);
                if (diagBlk) {
                    int grow = wm * 64 + mi * 32 + (r & 3) + 8 * (r >> 2) + 4 * h2;
                    int gcol = wn * 64 + ni * 32 + c31;
                    if (grow == gcol) e = 0.f;
                }
                rowpart[r] += e;
                colpart[ni] += e;
            }
        }
#pragma unroll
        for (int r = 0; r < 16; ++r) {
            float v = rowpart[r];
            v += __shfl_xor(v, 1);
            v += __shfl_xor(v, 2);
            v += __shfl_xor(v, 4);
            v += __shfl_xor(v, 8);
            v += __shfl_xor(v, 16);
            if (c31 == 0)
                atomicAdd(&rs_l[wm * 64 + mi * 32 + (r & 3) + 8 * (r >> 2) + 4 * h2], v);
        }
    }
#pragma unroll
    for (int ni = 0; ni < 2; ++ni) {
        float v = colpart[ni];
        v += __shfl_xor(v, 32);
        if (h2 == 0) atomicAdd(&cs_l[wn * 64 + ni * 32 + c31], v);
    }
    __syncthreads();
    if (tid < 128) atomicAdd(&row_sum[bm * 128 + tid], rs_l[tid]);
    else           atomicAdd(&col_sum[bn * 128 + (tid - 128)], cs_l[tid - 128]);
}

// loss = mean_i [ 2M + log(rs_i) + log(cs_i) - 2*diag_i ],  M = 1/temp
__global__ void finalize_kernel(const float* __restrict__ rs, const float* __restrict__ cs,
                                const float* __restrict__ dg, const float* __restrict__ temp,
                                float* __restrict__ out) {
    const float M = 1.0f / temp[0];
    float acc = 0.f;
    for (int i = threadIdx.x; i < N_ROWS; i += 256)
        acc += 2.f * M + __logf(rs[i]) + __logf(cs[i]) - 2.f * dg[i];
#pragma unroll
    for (int s = 1; s < 64; s <<= 1) acc += __shfl_xor(acc, s);
    __shared__ float wsum[4];
    if ((threadIdx.x & 63) == 0) wsum[threadIdx.x >> 6] = acc;
    __syncthreads();
    if (threadIdx.x == 0)
        out[0] = (wsum[0] + wsum[1] + wsum[2] + wsum[3]) / (float)N_ROWS;
}

extern "C" void kernel_launch(void* const* d_in, const int* in_sizes, int n_in,
                              void* d_out, int out_size, void* d_ws, size_t ws_size,
                              hipStream_t stream) {
    const float* cxr = (const float*)d_in[0];
    const float* ehr = (const float*)d_in[1];
    const float* temp = (const float*)d_in[2];
    float* out = (float*)d_out;

    char* ws = (char*)d_ws;
    unsigned char* Ab = (unsigned char*)ws;                        // 4 MB
    unsigned char* Bb = (unsigned char*)(ws + 4u * 1024 * 1024);   // 4 MB
    float* rs = (float*)(ws + 8u * 1024 * 1024);
    float* cs = rs + N_ROWS;
    float* dg = cs + N_ROWS;

    hipMemsetAsync(rs, 0, 2 * N_ROWS * sizeof(float), stream);
    normdiag_kernel<<<dim3(N_ROWS / 4), 256, 0, stream>>>(cxr, ehr, Ab, Bb, temp, dg);
    gemm_lse_kernel<<<dim3(64 * 64), 256, 0, stream>>>(Ab, Bb, temp, rs, cs);
    finalize_kernel<<<1, 256, 0, stream>>>(rs, cs, dg, temp, out);
}

// Round 13
// 134.861 us; speedup vs baseline: 1.5596x; 1.5596x over previous
//
#include <hip/hip_runtime.h>
#include <hip/hip_bf16.h>

#define N_ROWS 8192
#define D_DIM  512
#define NSTEPS 4    // K-steps of BK=128 fp8 bytes

typedef __attribute__((ext_vector_type(4))) int   i32x4;
typedef __attribute__((ext_vector_type(8))) int   i32x8;
typedef __attribute__((ext_vector_type(4))) float f32x4;

typedef const __attribute__((address_space(1))) void* gptr_t;
typedef __attribute__((address_space(3))) void* lptr_t;

static __device__ __forceinline__ void gload16(const void* g, void* l) {
    __builtin_amdgcn_global_load_lds((gptr_t)g, (lptr_t)l, 16, 0, 0);
}

// One wave per row-index i: L2-normalize cxr_i and ehr_i, write fp8 e4m3,
// and compute diag_i = dot(cxr_i,ehr_i)*ia*ib/temp (full fp32) in one pass.
__global__ void normdiag_kernel(const float* __restrict__ cxr, const float* __restrict__ ehr,
                                unsigned char* __restrict__ Ab, unsigned char* __restrict__ Bb,
                                const float* __restrict__ temp, float* __restrict__ dg) {
    const int row = blockIdx.x * 4 + (threadIdx.x >> 6);
    const int lane = threadIdx.x & 63;
    const float4* a4 = (const float4*)(cxr + (size_t)row * D_DIM + lane * 8);
    const float4* b4 = (const float4*)(ehr + (size_t)row * D_DIM + lane * 8);
    float4 a0 = a4[0], a1 = a4[1];
    float4 b0 = b4[0], b1 = b4[1];
    float sa = a0.x*a0.x + a0.y*a0.y + a0.z*a0.z + a0.w*a0.w
             + a1.x*a1.x + a1.y*a1.y + a1.z*a1.z + a1.w*a1.w;
    float sb = b0.x*b0.x + b0.y*b0.y + b0.z*b0.z + b0.w*b0.w
             + b1.x*b1.x + b1.y*b1.y + b1.z*b1.z + b1.w*b1.w;
    float dt = a0.x*b0.x + a0.y*b0.y + a0.z*b0.z + a0.w*b0.w
             + a1.x*b1.x + a1.y*b1.y + a1.z*b1.z + a1.w*b1.w;
#pragma unroll
    for (int s = 1; s < 64; s <<= 1) {
        sa += __shfl_xor(sa, s);
        sb += __shfl_xor(sb, s);
        dt += __shfl_xor(dt, s);
    }
    const float ia = 1.0f / sqrtf(fmaxf(sa, 1e-16f));
    const float ib = 1.0f / sqrtf(fmaxf(sb, 1e-16f));
    if (lane == 0) dg[row] = dt * ia * ib / temp[0];
    float va[8] = {a0.x, a0.y, a0.z, a0.w, a1.x, a1.y, a1.z, a1.w};
    float vb[8] = {b0.x, b0.y, b0.z, b0.w, b1.x, b1.y, b1.z, b1.w};
    int aw0 = __builtin_amdgcn_cvt_pk_fp8_f32(va[0]*ia, va[1]*ia, 0, false);
    aw0     = __builtin_amdgcn_cvt_pk_fp8_f32(va[2]*ia, va[3]*ia, aw0, true);
    int aw1 = __builtin_amdgcn_cvt_pk_fp8_f32(va[4]*ia, va[5]*ia, 0, false);
    aw1     = __builtin_amdgcn_cvt_pk_fp8_f32(va[6]*ia, va[7]*ia, aw1, true);
    int bw0 = __builtin_amdgcn_cvt_pk_fp8_f32(vb[0]*ib, vb[1]*ib, 0, false);
    bw0     = __builtin_amdgcn_cvt_pk_fp8_f32(vb[2]*ib, vb[3]*ib, bw0, true);
    int bw1 = __builtin_amdgcn_cvt_pk_fp8_f32(vb[4]*ib, vb[5]*ib, 0, false);
    bw1     = __builtin_amdgcn_cvt_pk_fp8_f32(vb[6]*ib, vb[7]*ib, bw1, true);
    *(int2*)(Ab + (size_t)row * D_DIM + lane * 8) = make_int2(aw0, aw1);
    *(int2*)(Bb + (size_t)row * D_DIM + lane * 8) = make_int2(bw0, bw1);
}

// by-value 32-byte fragment from two (possibly non-adjacent) 16-B LDS slots
static __device__ __forceinline__ i32x8 ld2(const unsigned char* p0, const unsigned char* p1) {
    i32x4 lo = *(const i32x4*)p0;
    i32x4 hi = *(const i32x4*)p1;
    return (i32x8){lo[0], lo[1], lo[2], lo[3], hi[0], hi[1], hi[2], hi[3]};
}

// fp8 128x64 GEMM via mfma_scale_f32_16x16x128_f8f6f4 (scale=1.0), BK=128:
// 16-row fragment reads on 128-B LDS rows with slot^((row>>1)&7) swizzle -- the
// zero-bank-conflict geometry (r3-proven). 4 waves (2x2), wave tile 64x32,
// acc f32x4[4][2]=32 regs, ~95 live -> no spill. Double-buffered LDS (48 KB),
// 3 blocks/CU = 12 waves in 3 independent barrier domains. 4 K-steps.
// Epilogue: exp((cos-1)/T), diag zeroed, row/col sums -> global atomics.
__global__ __launch_bounds__(256, 3) void gemm_lse_kernel(
        const unsigned char* __restrict__ A, const unsigned char* __restrict__ B,
        const float* __restrict__ temp,
        float* __restrict__ row_sum, float* __restrict__ col_sum) {
    __shared__ unsigned char As[2][128 * 128];   // [buf][row][128 B] = 2 x 16 KB
    __shared__ unsigned char Bs[2][64 * 128];    // 2 x 8 KB
    __shared__ float rs_l[128];
    __shared__ float cs_l[64];

    const int tid = threadIdx.x;
    const int lane = tid & 63;
    const int wid = tid >> 6;                 // 4 waves
    const int bm = blockIdx.x & 63;           // 128-row band; bm-major
    const int bn = blockIdx.x >> 6;           // 64-col band
    const int wm = wid >> 1, wn = wid & 1;    // wave tile 64x32

    if (tid < 128) rs_l[tid] = 0.f;
    else if (tid < 192) cs_l[tid - 128] = 0.f;

    // ---- staging: each gload = 8 rows x 128 B, linear LDS dest base+lane*16.
    // lane l -> row R+(l>>3), slot l&7. Content must be global slot
    // (l&7)^swz(row), swz(row)=((row>>1)&7) = ((l>>4)&3) ^ (4*((R>>3)&1)).
    const int l7 = lane & 7, l34 = (lane >> 4) & 3, lrow8 = lane >> 3;
    const int src_even = (l7 ^ l34) * 16;        // chunks with (R>>3) even
    const int src_odd  = (l7 ^ l34 ^ 4) * 16;    // chunks with (R>>3) odd
    // per-matrix row base for this lane within a chunk
    const unsigned char* gA = A + (size_t)(bm * 128 + lrow8) * D_DIM;
    const unsigned char* gB = B + (size_t)(bn * 64  + lrow8) * D_DIM;

    // A: wave stages rows wid*32 + c*8, c=0..3 ; B: rows wid*16 + c*8, c=0..1
#define STG_A(d, c, st) gload16(gA + (size_t)(wid * 32 + (c) * 8) * D_DIM + (st) * 128 \
                                   + (((c) & 1) ? src_odd : src_even), \
                                &As[d][(wid * 32 + (c) * 8) * 128])
#define STG_B(d, c, st) gload16(gB + (size_t)(wid * 16 + (c) * 8) * D_DIM + (st) * 128 \
                                   + ((((wid * 2 + (c)) & 1)) ? src_odd : src_even), \
                                &Bs[d][(wid * 16 + (c) * 8) * 128])
#define STAGE(d, st) do { \
    STG_A(d, 0, st); STG_A(d, 1, st); STG_A(d, 2, st); STG_A(d, 3, st); \
    STG_B(d, 0, st); STG_B(d, 1, st); } while (0)

    // ---- fragment reads: lane l -> row (tile*16 + (l&15)), k-group l>>4.
    // LDS slot of global slot g at row r: g ^ ((r&15)>>1 ... swz=(rl>>1)&7).
    const int rl = lane & 15, kg = lane >> 4;
    const int so0 = ((2 * kg) ^ ((rl >> 1) & 7)) * 16;   // so1 = so0 ^ 16

    f32x4 acc[4][2] = {};
    const int sc = 0x7F7F7F7F;   // E8M0 127 -> scale 1.0

    STAGE(0, 0);
    __syncthreads();

#pragma unroll
    for (int s = 0; s < NSTEPS; ++s) {
        const int d = s & 1;
        if (s + 1 < NSTEPS) STAGE(d ^ 1, s + 1);

        i32x8 Af[4];
#pragma unroll
        for (int i = 0; i < 4; ++i) {
            const unsigned char* rp = &As[d][(wm * 64 + i * 16 + rl) * 128];
            Af[i] = ld2(rp + so0, rp + (so0 ^ 16));
        }
#pragma unroll
        for (int j = 0; j < 2; ++j) {
            const unsigned char* rp = &Bs[d][(wn * 32 + j * 16 + rl) * 128];
            i32x8 Bf = ld2(rp + so0, rp + (so0 ^ 16));
#pragma unroll
            for (int i = 0; i < 4; ++i)
                acc[i][j] = __builtin_amdgcn_mfma_scale_f32_16x16x128_f8f6f4(
                    Af[i], Bf, acc[i][j], 0, 0, 0, sc, 0, sc);
        }
        if (s + 1 < NSTEPS) __syncthreads();
    }

    // ---- epilogue: exp + masked diag + row/col reduction ----
    // C/D 16x16 layout: col = lane&15, row = (lane>>4)*4 + reg
    const float invT = 1.0f / temp[0];
    const bool diagBlk = ((bm >> 1) == bn >> 0) ? ((bn >> 1) == bm) : false;
    // diag intersects when bm*128..+128 overlaps bn*64..+64  <=>  (bn>>1)==bm
    const bool dBlk = ((bn >> 1) == bm);
    float colpart[2] = {0.f, 0.f};
    (void)diagBlk;

#pragma unroll
    for (int i = 0; i < 4; ++i) {
        float rp4[4] = {0.f, 0.f, 0.f, 0.f};
#pragma unroll
        for (int j = 0; j < 2; ++j) {
            f32x4 a = acc[i][j];
#pragma unroll
            for (int r = 0; r < 4; ++r) {
                float e = __expf((a[r] - 1.0f) * invT);
                if (dBlk) {
                    int grow = bm * 128 + wm * 64 + i * 16 + kg * 4 + r;
                    int gcol = bn * 64 + wn * 32 + j * 16 + rl;
                    if (grow == gcol) e = 0.f;
                }
                rp4[r] += e;
                colpart[j] += e;
            }
        }
        // row sums: reduce across the 16 cols (lanes sharing kg)
#pragma unroll
        for (int r = 0; r < 4; ++r) {
            float v = rp4[r];
            v += __shfl_xor(v, 1);
            v += __shfl_xor(v, 2);
            v += __shfl_xor(v, 4);
            v += __shfl_xor(v, 8);
            if (rl == 0)
                atomicAdd(&rs_l[wm * 64 + i * 16 + kg * 4 + r], v);
        }
    }
    // col sums: reduce across the 4 kg groups
#pragma unroll
    for (int j = 0; j < 2; ++j) {
        float v = colpart[j];
        v += __shfl_xor(v, 16);
        v += __shfl_xor(v, 32);
        if (kg == 0) atomicAdd(&cs_l[wn * 32 + j * 16 + rl], v);
    }
    __syncthreads();
    if (tid < 128) atomicAdd(&row_sum[bm * 128 + tid], rs_l[tid]);
    else if (tid < 192) atomicAdd(&col_sum[bn * 64 + (tid - 128)], cs_l[tid - 128]);
}

// loss = mean_i [ 2M + log(rs_i) + log(cs_i) - 2*diag_i ],  M = 1/temp
__global__ void finalize_kernel(const float* __restrict__ rs, const float* __restrict__ cs,
                                const float* __restrict__ dg, const float* __restrict__ temp,
                                float* __restrict__ out) {
    const float M = 1.0f / temp[0];
    float acc = 0.f;
    for (int i = threadIdx.x; i < N_ROWS; i += 256)
        acc += 2.f * M + __logf(rs[i]) + __logf(cs[i]) - 2.f * dg[i];
#pragma unroll
    for (int s = 1; s < 64; s <<= 1) acc += __shfl_xor(acc, s);
    __shared__ float wsum[4];
    if ((threadIdx.x & 63) == 0) wsum[threadIdx.x >> 6] = acc;
    __syncthreads();
    if (threadIdx.x == 0)
        out[0] = (wsum[0] + wsum[1] + wsum[2] + wsum[3]) / (float)N_ROWS;
}

extern "C" void kernel_launch(void* const* d_in, const int* in_sizes, int n_in,
                              void* d_out, int out_size, void* d_ws, size_t ws_size,
                              hipStream_t stream) {
    const float* cxr = (const float*)d_in[0];
    const float* ehr = (const float*)d_in[1];
    const float* temp = (const float*)d_in[2];
    float* out = (float*)d_out;

    char* ws = (char*)d_ws;
    unsigned char* Ab = (unsigned char*)ws;                        // 4 MB
    unsigned char* Bb = (unsigned char*)(ws + 4u * 1024 * 1024);   // 4 MB
    float* rs = (float*)(ws + 8u * 1024 * 1024);
    float* cs = rs + N_ROWS;
    float* dg = cs + N_ROWS;

    hipMemsetAsync(rs, 0, 2 * N_ROWS * sizeof(float), stream);
    normdiag_kernel<<<dim3(N_ROWS / 4), 256, 0, stream>>>(cxr, ehr, Ab, Bb, temp, dg);
    gemm_lse_kernel<<<dim3(128 * 64), 256, 0, stream>>>(Ab, Bb, temp, rs, cs);
    finalize_kernel<<<1, 256, 0, stream>>>(rs, cs, dg, temp, out);
}

// Round 14
// 105.865 us; speedup vs baseline: 1.9868x; 1.2739x over previous
//
#include <hip/hip_runtime.h>
#include <hip/hip_bf16.h>

#define N_ROWS 8192
#define D_DIM  512
#define NSTEPS 8    // K-steps of BK=64 fp8 bytes

typedef __attribute__((ext_vector_type(4))) int   i32x4;
typedef __attribute__((ext_vector_type(8))) int   i32x8;
typedef __attribute__((ext_vector_type(16))) float f32x16;

typedef const __attribute__((address_space(1))) void* gptr_t;
typedef __attribute__((address_space(3))) void* lptr_t;

static __device__ __forceinline__ void gload16(const void* g, void* l) {
    __builtin_amdgcn_global_load_lds((gptr_t)g, (lptr_t)l, 16, 0, 0);
}
#define VMCNT(n)  asm volatile("s_waitcnt vmcnt(" #n ")" ::: "memory")
#define BARRIER() __builtin_amdgcn_s_barrier()
#define SCHED0()  __builtin_amdgcn_sched_barrier(0)

// One wave per row-index i: L2-normalize cxr_i and ehr_i, write fp8 e4m3,
// and compute diag_i = dot(cxr_i,ehr_i)*ia*ib/temp (full fp32) in one pass.
__global__ void normdiag_kernel(const float* __restrict__ cxr, const float* __restrict__ ehr,
                                unsigned char* __restrict__ Ab, unsigned char* __restrict__ Bb,
                                const float* __restrict__ temp, float* __restrict__ dg) {
    const int row = blockIdx.x * 4 + (threadIdx.x >> 6);
    const int lane = threadIdx.x & 63;
    const float4* a4 = (const float4*)(cxr + (size_t)row * D_DIM + lane * 8);
    const float4* b4 = (const float4*)(ehr + (size_t)row * D_DIM + lane * 8);
    float4 a0 = a4[0], a1 = a4[1];
    float4 b0 = b4[0], b1 = b4[1];
    float sa = a0.x*a0.x + a0.y*a0.y + a0.z*a0.z + a0.w*a0.w
             + a1.x*a1.x + a1.y*a1.y + a1.z*a1.z + a1.w*a1.w;
    float sb = b0.x*b0.x + b0.y*b0.y + b0.z*b0.z + b0.w*b0.w
             + b1.x*b1.x + b1.y*b1.y + b1.z*b1.z + b1.w*b1.w;
    float dt = a0.x*b0.x + a0.y*b0.y + a0.z*b0.z + a0.w*b0.w
             + a1.x*b1.x + a1.y*b1.y + a1.z*b1.z + a1.w*b1.w;
#pragma unroll
    for (int s = 1; s < 64; s <<= 1) {
        sa += __shfl_xor(sa, s);
        sb += __shfl_xor(sb, s);
        dt += __shfl_xor(dt, s);
    }
    const float ia = 1.0f / sqrtf(fmaxf(sa, 1e-16f));
    const float ib = 1.0f / sqrtf(fmaxf(sb, 1e-16f));
    if (lane == 0) dg[row] = dt * ia * ib / temp[0];
    float va[8] = {a0.x, a0.y, a0.z, a0.w, a1.x, a1.y, a1.z, a1.w};
    float vb[8] = {b0.x, b0.y, b0.z, b0.w, b1.x, b1.y, b1.z, b1.w};
    int aw0 = __builtin_amdgcn_cvt_pk_fp8_f32(va[0]*ia, va[1]*ia, 0, false);
    aw0     = __builtin_amdgcn_cvt_pk_fp8_f32(va[2]*ia, va[3]*ia, aw0, true);
    int aw1 = __builtin_amdgcn_cvt_pk_fp8_f32(va[4]*ia, va[5]*ia, 0, false);
    aw1     = __builtin_amdgcn_cvt_pk_fp8_f32(va[6]*ia, va[7]*ia, aw1, true);
    int bw0 = __builtin_amdgcn_cvt_pk_fp8_f32(vb[0]*ib, vb[1]*ib, 0, false);
    bw0     = __builtin_amdgcn_cvt_pk_fp8_f32(vb[2]*ib, vb[3]*ib, bw0, true);
    int bw1 = __builtin_amdgcn_cvt_pk_fp8_f32(vb[4]*ib, vb[5]*ib, 0, false);
    bw1     = __builtin_amdgcn_cvt_pk_fp8_f32(vb[6]*ib, vb[7]*ib, bw1, true);
    *(int2*)(Ab + (size_t)row * D_DIM + lane * 8) = make_int2(aw0, aw1);
    *(int2*)(Bb + (size_t)row * D_DIM + lane * 8) = make_int2(bw0, bw1);
}

// by-value 32-byte fragment from two 16-B LDS slots (the r9/r10 no-alloca idiom)
static __device__ __forceinline__ i32x8 ld2(const unsigned char* p0, const unsigned char* p1) {
    i32x4 lo = *(const i32x4*)p0;
    i32x4 hi = *(const i32x4*)(p1);
    return (i32x8){lo[0], lo[1], lo[2], lo[3], hi[0], hi[1], hi[2], hi[3]};
}

// fp8 128x128 GEMM computing BOTH E = exp-tile and E^T per wave:
// accT = mfma(Bf, Af) reuses the same staged fragments (operand layouts are
// symmetric), making ROW sums lane-local like col sums -> the shuffle-storm
// epilogue (80+ ds_bpermute/lane, 13-round constant) collapses to reg-sums +
// one shfl_xor(32) + LDS atomics. 8 waves (2x4), wave tile 64x32,
// acc[2]+accT[2] f32x16 + Af[2]+Bf -> ~105 regs ((512,2) proven clean, r9).
// Ring-3 LDS 48 KB, counted VMCNT(2). Epilogue: exp((cos-1)/T), diag zeroed.
__global__ __launch_bounds__(512, 2) void gemm_lse_kernel(
        const unsigned char* __restrict__ A, const unsigned char* __restrict__ B,
        const float* __restrict__ temp,
        float* __restrict__ row_sum, float* __restrict__ col_sum) {
    __shared__ unsigned char As[3][8192];    // [buf][128 rows][64 B] = 3 x 8 KB
    __shared__ unsigned char Bs[3][8192];
    __shared__ float rs_l[128];
    __shared__ float cs_l[128];

    const int tid = threadIdx.x;
    const int lane = tid & 63;
    const int wid = tid >> 6;                 // 8 waves
    const int bm = blockIdx.x & 63;           // bm-major for B-panel L2 reuse
    const int bn = blockIdx.x >> 6;
    const int wm = wid >> 2, wn = wid & 3;    // wave tile 64x32

    if (tid < 128) rs_l[tid] = 0.f;
    else if (tid < 256) cs_l[tid - 128] = 0.f;

    // staging: wave stages A rows wid*16..+16 and B rows wid*16..+16 (1 gload
    // each: 64 lanes x 16 B = 16 rows x 64 B). Linear LDS dest; T2 source
    // swizzle: lane l -> row base+(l>>2), slot l&3, source slot (l&3)^((l>>3)&3).
    const int swz = ((lane & 3) ^ ((lane >> 3) & 3)) * 16;
    const unsigned char* gA = A + (size_t)(bm * 128 + wid * 16 + (lane >> 2)) * D_DIM + swz;
    const unsigned char* gB = B + (size_t)(bn * 128 + wid * 16 + (lane >> 2)) * D_DIM + swz;

#define STG(d, st) do { \
    gload16(gA + (st) * 64, &As[d][(wid * 16) * 64]); \
    gload16(gB + (st) * 64, &Bs[d][(wid * 16) * 64]); } while (0)

    // fragment reads: lane covers row base+c31, k-half h2 (32 B = 2 b128).
    // LDS slot of global slot g at row r: g ^ ((r>>1)&3); (r>>1)&3 = (c31>>1)&3.
    const int c31 = lane & 31, h2 = lane >> 5;
    const int so0 = (((2 * h2) ^ ((c31 >> 1) & 3)) & 3) * 16;

    f32x16 acc[2] = {};    // E quadrants (mi)
    f32x16 accT[2] = {};   // E^T quadrants (mi)
    const int sc = 0x7F7F7F7F;   // E8M0 127 -> scale 1.0

    // prologue: stage steps 0,1 (2 gloads/wave each); drain step 0, keep 1 flying
    STG(0, 0);
    STG(1, 1);
    VMCNT(2);
    BARRIER(); SCHED0();

#pragma unroll
    for (int s = 0; s < NSTEPS; ++s) {
        const int d = s % 3;
        if (s + 2 < NSTEPS) STG((s + 2) % 3, s + 2);

        i32x8 Af0, Af1, Bf;
        {
            const unsigned char* rp = &As[d][(wm * 64 + c31) * 64];
            Af0 = ld2(rp + so0, rp + (so0 ^ 16));
            rp += 32 * 64;
            Af1 = ld2(rp + so0, rp + (so0 ^ 16));
            const unsigned char* bp = &Bs[d][(wn * 32 + c31) * 64];
            Bf = ld2(bp + so0, bp + (so0 ^ 16));
        }
        acc[0]  = __builtin_amdgcn_mfma_scale_f32_32x32x64_f8f6f4(Af0, Bf, acc[0],  0, 0, 0, sc, 0, sc);
        acc[1]  = __builtin_amdgcn_mfma_scale_f32_32x32x64_f8f6f4(Af1, Bf, acc[1],  0, 0, 0, sc, 0, sc);
        accT[0] = __builtin_amdgcn_mfma_scale_f32_32x32x64_f8f6f4(Bf, Af0, accT[0], 0, 0, 0, sc, 0, sc);
        accT[1] = __builtin_amdgcn_mfma_scale_f32_32x32x64_f8f6f4(Bf, Af1, accT[1], 0, 0, 0, sc, 0, sc);

        // boundary: certify step s+1 landed for all waves; keep s+2 flying
        if (s <= NSTEPS - 3)       { VMCNT(2); BARRIER(); SCHED0(); }
        else if (s == NSTEPS - 2)  { VMCNT(0); BARRIER(); SCHED0(); }
    }

    // ---- epilogue: lane-local sums, no shuffle storm ----
    // C/D 32x32 layout: col = lane&31, row = (reg&3) + 8*(reg>>2) + 4*(lane>>5)
    const float invT = 1.0f / temp[0];
    const bool dBlk = (bm == bn);

    // E: lane owns col j = bn*128 + wn*32 + c31; rows i = bm*128 + wm*64 + mi*32 + rowof
    float csum = 0.f;
#pragma unroll
    for (int mi = 0; mi < 2; ++mi) {
        f32x16 a = acc[mi];
#pragma unroll
        for (int r = 0; r < 16; ++r) {
            float e = __expf((a[r] - 1.0f) * invT);
            if (dBlk) {
                int grow = wm * 64 + mi * 32 + (r & 3) + 8 * (r >> 2) + 4 * h2;
                int gcol = wn * 32 + c31;
                if (grow == gcol) e = 0.f;
            }
            csum += e;
        }
    }
    csum += __shfl_xor(csum, 32);
    if (h2 == 0) atomicAdd(&cs_l[wn * 32 + c31], csum);

    // E^T: lane owns col i = bm*128 + wm*64 + mi*32 + c31; rows j = bn*128 + wn*32 + rowof
#pragma unroll
    for (int mi = 0; mi < 2; ++mi) {
        f32x16 a = accT[mi];
        float rsum = 0.f;
#pragma unroll
        for (int r = 0; r < 16; ++r) {
            float e = __expf((a[r] - 1.0f) * invT);
            if (dBlk) {
                int grow = wn * 32 + (r & 3) + 8 * (r >> 2) + 4 * h2;
                int gcol = wm * 64 + mi * 32 + c31;
                if (grow == gcol) e = 0.f;
            }
            rsum += e;
        }
        rsum += __shfl_xor(rsum, 32);
        if (h2 == 0) atomicAdd(&rs_l[wm * 64 + mi * 32 + c31], rsum);
    }
    __syncthreads();
    if (tid < 128) atomicAdd(&row_sum[bm * 128 + tid], rs_l[tid]);
    else if (tid < 256) atomicAdd(&col_sum[bn * 128 + (tid - 128)], cs_l[tid - 128]);
}

// loss = mean_i [ 2M + log(rs_i) + log(cs_i) - 2*diag_i ],  M = 1/temp
__global__ void finalize_kernel(const float* __restrict__ rs, const float* __restrict__ cs,
                                const float* __restrict__ dg, const float* __restrict__ temp,
                                float* __restrict__ out) {
    const float M = 1.0f / temp[0];
    float acc = 0.f;
    for (int i = threadIdx.x; i < N_ROWS; i += 256)
        acc += 2.f * M + __logf(rs[i]) + __logf(cs[i]) - 2.f * dg[i];
#pragma unroll
    for (int s = 1; s < 64; s <<= 1) acc += __shfl_xor(acc, s);
    __shared__ float wsum[4];
    if ((threadIdx.x & 63) == 0) wsum[threadIdx.x >> 6] = acc;
    __syncthreads();
    if (threadIdx.x == 0)
        out[0] = (wsum[0] + wsum[1] + wsum[2] + wsum[3]) / (float)N_ROWS;
}

extern "C" void kernel_launch(void* const* d_in, const int* in_sizes, int n_in,
                              void* d_out, int out_size, void* d_ws, size_t ws_size,
                              hipStream_t stream) {
    const float* cxr = (const float*)d_in[0];
    const float* ehr = (const float*)d_in[1];
    const float* temp = (const float*)d_in[2];
    float* out = (float*)d_out;

    char* ws = (char*)d_ws;
    unsigned char* Ab = (unsigned char*)ws;                        // 4 MB
    unsigned char* Bb = (unsigned char*)(ws + 4u * 1024 * 1024);   // 4 MB
    float* rs = (float*)(ws + 8u * 1024 * 1024);
    float* cs = rs + N_ROWS;
    float* dg = cs + N_ROWS;

    hipMemsetAsync(rs, 0, 2 * N_ROWS * sizeof(float), stream);
    normdiag_kernel<<<dim3(N_ROWS / 4), 256, 0, stream>>>(cxr, ehr, Ab, Bb, temp, dg);
    gemm_lse_kernel<<<dim3(64 * 64), 512, 0, stream>>>(Ab, Bb, temp, rs, cs);
    finalize_kernel<<<1, 256, 0, stream>>>(rs, cs, dg, temp, out);
}

// Round 15
// 97.787 us; speedup vs baseline: 2.1509x; 1.0826x over previous
//
#include <hip/hip_runtime.h>
#include <hip/hip_bf16.h>

#define N_ROWS 8192
#define D_DIM  512
#define NSTEPS 8    // K-steps of BK=64 fp8 bytes

typedef __attribute__((ext_vector_type(4))) int   i32x4;
typedef __attribute__((ext_vector_type(8))) int   i32x8;
typedef __attribute__((ext_vector_type(16))) float f32x16;

typedef const __attribute__((address_space(1))) void* gptr_t;
typedef __attribute__((address_space(3))) void* lptr_t;

static __device__ __forceinline__ void gload16(const void* g, void* l) {
    __builtin_amdgcn_global_load_lds((gptr_t)g, (lptr_t)l, 16, 0, 0);
}
#define VMCNT(n)  asm volatile("s_waitcnt vmcnt(" #n ")" ::: "memory")
#define BARRIER() __builtin_amdgcn_s_barrier()
#define SCHED0()  __builtin_amdgcn_sched_barrier(0)

// One wave per row-index i: L2-normalize cxr_i and ehr_i, write fp8 e4m3,
// and compute diag_i = dot(cxr_i,ehr_i)*ia*ib/temp (full fp32) in one pass.
__global__ void normdiag_kernel(const float* __restrict__ cxr, const float* __restrict__ ehr,
                                unsigned char* __restrict__ Ab, unsigned char* __restrict__ Bb,
                                const float* __restrict__ temp, float* __restrict__ dg) {
    const int row = blockIdx.x * 4 + (threadIdx.x >> 6);
    const int lane = threadIdx.x & 63;
    const float4* a4 = (const float4*)(cxr + (size_t)row * D_DIM + lane * 8);
    const float4* b4 = (const float4*)(ehr + (size_t)row * D_DIM + lane * 8);
    float4 a0 = a4[0], a1 = a4[1];
    float4 b0 = b4[0], b1 = b4[1];
    float sa = a0.x*a0.x + a0.y*a0.y + a0.z*a0.z + a0.w*a0.w
             + a1.x*a1.x + a1.y*a1.y + a1.z*a1.z + a1.w*a1.w;
    float sb = b0.x*b0.x + b0.y*b0.y + b0.z*b0.z + b0.w*b0.w
             + b1.x*b1.x + b1.y*b1.y + b1.z*b1.z + b1.w*b1.w;
    float dt = a0.x*b0.x + a0.y*b0.y + a0.z*b0.z + a0.w*b0.w
             + a1.x*b1.x + a1.y*b1.y + a1.z*b1.z + a1.w*b1.w;
#pragma unroll
    for (int s = 1; s < 64; s <<= 1) {
        sa += __shfl_xor(sa, s);
        sb += __shfl_xor(sb, s);
        dt += __shfl_xor(dt, s);
    }
    const float ia = 1.0f / sqrtf(fmaxf(sa, 1e-16f));
    const float ib = 1.0f / sqrtf(fmaxf(sb, 1e-16f));
    if (lane == 0) dg[row] = dt * ia * ib / temp[0];
    float va[8] = {a0.x, a0.y, a0.z, a0.w, a1.x, a1.y, a1.z, a1.w};
    float vb[8] = {b0.x, b0.y, b0.z, b0.w, b1.x, b1.y, b1.z, b1.w};
    int aw0 = __builtin_amdgcn_cvt_pk_fp8_f32(va[0]*ia, va[1]*ia, 0, false);
    aw0     = __builtin_amdgcn_cvt_pk_fp8_f32(va[2]*ia, va[3]*ia, aw0, true);
    int aw1 = __builtin_amdgcn_cvt_pk_fp8_f32(va[4]*ia, va[5]*ia, 0, false);
    aw1     = __builtin_amdgcn_cvt_pk_fp8_f32(va[6]*ia, va[7]*ia, aw1, true);
    int bw0 = __builtin_amdgcn_cvt_pk_fp8_f32(vb[0]*ib, vb[1]*ib, 0, false);
    bw0     = __builtin_amdgcn_cvt_pk_fp8_f32(vb[2]*ib, vb[3]*ib, bw0, true);
    int bw1 = __builtin_amdgcn_cvt_pk_fp8_f32(vb[4]*ib, vb[5]*ib, 0, false);
    bw1     = __builtin_amdgcn_cvt_pk_fp8_f32(vb[6]*ib, vb[7]*ib, bw1, true);
    *(int2*)(Ab + (size_t)row * D_DIM + lane * 8) = make_int2(aw0, aw1);
    *(int2*)(Bb + (size_t)row * D_DIM + lane * 8) = make_int2(bw0, bw1);
}

// by-value 32-byte fragment from two 16-B LDS slots (the r9/r10 no-alloca idiom)
static __device__ __forceinline__ i32x8 ld2(const unsigned char* p0, const unsigned char* p1) {
    i32x4 lo = *(const i32x4*)p0;
    i32x4 hi = *(const i32x4*)(p1);
    return (i32x8){lo[0], lo[1], lo[2], lo[3], hi[0], hi[1], hi[2], hi[3]};
}

// fp8 128x128 GEMM, E + E^T per wave (lane-local row AND col sums, r14-proven).
// r15 delta: ring-2 LDS (32 KB) -> 4 independent blocks/CU (~32 waves) to lift
// the 39% occupancy that capped r14 at MfmaUtil 34%. Boundary = VMCNT(0)+barrier
// (drain covers only my wave's 2 loads, issued one full compute-phase earlier;
// cross-block TLP fills the gap). 8 waves (2x4), wave tile 64x32, VGPR ~60.
__global__ __launch_bounds__(512, 2) void gemm_lse_kernel(
        const unsigned char* __restrict__ A, const unsigned char* __restrict__ B,
        const float* __restrict__ temp,
        float* __restrict__ row_sum, float* __restrict__ col_sum) {
    __shared__ unsigned char As[2][8192];    // [buf][128 rows][64 B] = 2 x 8 KB
    __shared__ unsigned char Bs[2][8192];
    __shared__ float rs_l[128];
    __shared__ float cs_l[128];

    const int tid = threadIdx.x;
    const int lane = tid & 63;
    const int wid = tid >> 6;                 // 8 waves
    const int bm = blockIdx.x & 63;           // bm-major for B-panel L2 reuse
    const int bn = blockIdx.x >> 6;
    const int wm = wid >> 2, wn = wid & 3;    // wave tile 64x32

    if (tid < 128) rs_l[tid] = 0.f;
    else if (tid < 256) cs_l[tid - 128] = 0.f;

    // staging: wave stages A rows wid*16..+16 and B rows wid*16..+16 (1 gload
    // each). Linear LDS dest; T2 source swizzle: lane l -> row base+(l>>2),
    // slot l&3, source slot (l&3)^((l>>3)&3).
    const int swz = ((lane & 3) ^ ((lane >> 3) & 3)) * 16;
    const unsigned char* gA = A + (size_t)(bm * 128 + wid * 16 + (lane >> 2)) * D_DIM + swz;
    const unsigned char* gB = B + (size_t)(bn * 128 + wid * 16 + (lane >> 2)) * D_DIM + swz;

#define STG(d, st) do { \
    gload16(gA + (st) * 64, &As[d][(wid * 16) * 64]); \
    gload16(gB + (st) * 64, &Bs[d][(wid * 16) * 64]); } while (0)

    // fragment reads: lane covers row base+c31, k-half h2 (32 B = 2 b128).
    // LDS slot of global slot g at row r: g ^ ((r>>1)&3); (r>>1)&3 = (c31>>1)&3.
    const int c31 = lane & 31, h2 = lane >> 5;
    const int so0 = (((2 * h2) ^ ((c31 >> 1) & 3)) & 3) * 16;

    f32x16 acc[2] = {};    // E quadrants (mi)
    f32x16 accT[2] = {};   // E^T quadrants (mi)
    const int sc = 0x7F7F7F7F;   // E8M0 127 -> scale 1.0

    // prologue: stage step 0, drain, barrier
    STG(0, 0);
    VMCNT(0);
    BARRIER(); SCHED0();

#pragma unroll
    for (int s = 0; s < NSTEPS; ++s) {
        const int d = s & 1;
        if (s + 1 < NSTEPS) STG(d ^ 1, s + 1);   // buf d^1 was fully read in step s-1

        i32x8 Af0, Af1, Bf;
        {
            const unsigned char* rp = &As[d][(wm * 64 + c31) * 64];
            Af0 = ld2(rp + so0, rp + (so0 ^ 16));
            rp += 32 * 64;
            Af1 = ld2(rp + so0, rp + (so0 ^ 16));
            const unsigned char* bp = &Bs[d][(wn * 32 + c31) * 64];
            Bf = ld2(bp + so0, bp + (so0 ^ 16));
        }
        acc[0]  = __builtin_amdgcn_mfma_scale_f32_32x32x64_f8f6f4(Af0, Bf, acc[0],  0, 0, 0, sc, 0, sc);
        acc[1]  = __builtin_amdgcn_mfma_scale_f32_32x32x64_f8f6f4(Af1, Bf, acc[1],  0, 0, 0, sc, 0, sc);
        accT[0] = __builtin_amdgcn_mfma_scale_f32_32x32x64_f8f6f4(Bf, Af0, accT[0], 0, 0, 0, sc, 0, sc);
        accT[1] = __builtin_amdgcn_mfma_scale_f32_32x32x64_f8f6f4(Bf, Af1, accT[1], 0, 0, 0, sc, 0, sc);

        // boundary: drain my stage(s+1) (issued before this step's compute) and
        // sync so buf[d] can be overwritten next step.
        if (s + 1 < NSTEPS) { VMCNT(0); BARRIER(); SCHED0(); }
    }

    // ---- epilogue: lane-local sums, no shuffle storm ----
    // C/D 32x32 layout: col = lane&31, row = (reg&3) + 8*(reg>>2) + 4*(lane>>5)
    const float invT = 1.0f / temp[0];
    const bool dBlk = (bm == bn);

    // E: lane owns col j = wn*32 + c31; rows i = wm*64 + mi*32 + rowof(r,h2)
    float csum = 0.f;
#pragma unroll
    for (int mi = 0; mi < 2; ++mi) {
        f32x16 a = acc[mi];
#pragma unroll
        for (int r = 0; r < 16; ++r) {
            float e = __expf((a[r] - 1.0f) * invT);
            if (dBlk) {
                int grow = wm * 64 + mi * 32 + (r & 3) + 8 * (r >> 2) + 4 * h2;
                int gcol = wn * 32 + c31;
                if (grow == gcol) e = 0.f;
            }
            csum += e;
        }
    }
    csum += __shfl_xor(csum, 32);
    if (h2 == 0) atomicAdd(&cs_l[wn * 32 + c31], csum);

    // E^T: lane owns col i = wm*64 + mi*32 + c31; rows j = wn*32 + rowof(r,h2)
#pragma unroll
    for (int mi = 0; mi < 2; ++mi) {
        f32x16 a = accT[mi];
        float rsum = 0.f;
#pragma unroll
        for (int r = 0; r < 16; ++r) {
            float e = __expf((a[r] - 1.0f) * invT);
            if (dBlk) {
                int grow = wn * 32 + (r & 3) + 8 * (r >> 2) + 4 * h2;
                int gcol = wm * 64 + mi * 32 + c31;
                if (grow == gcol) e = 0.f;
            }
            rsum += e;
        }
        rsum += __shfl_xor(rsum, 32);
        if (h2 == 0) atomicAdd(&rs_l[wm * 64 + mi * 32 + c31], rsum);
    }
    __syncthreads();
    if (tid < 128) atomicAdd(&row_sum[bm * 128 + tid], rs_l[tid]);
    else if (tid < 256) atomicAdd(&col_sum[bn * 128 + (tid - 128)], cs_l[tid - 128]);
}

// loss = mean_i [ 2M + log(rs_i) + log(cs_i) - 2*diag_i ],  M = 1/temp
// 16 blocks x 512 threads, one row index per thread; block sums atomicAdd into
// out[0] (pre-zeroed via hipMemsetAsync).
__global__ void finalize_kernel(const float* __restrict__ rs, const float* __restrict__ cs,
                                const float* __restrict__ dg, const float* __restrict__ temp,
                                float* __restrict__ out) {
    const float M = 1.0f / temp[0];
    const int i = blockIdx.x * 512 + threadIdx.x;
    float acc = 2.f * M + __logf(rs[i]) + __logf(cs[i]) - 2.f * dg[i];
#pragma unroll
    for (int s = 1; s < 64; s <<= 1) acc += __shfl_xor(acc, s);
    __shared__ float wsum[8];
    if ((threadIdx.x & 63) == 0) wsum[threadIdx.x >> 6] = acc;
    __syncthreads();
    if (threadIdx.x == 0) {
        float t = 0.f;
#pragma unroll
        for (int w = 0; w < 8; ++w) t += wsum[w];
        atomicAdd(out, t * (-1.0f / (float)N_ROWS) * -1.0f / 1.0f);   // t / N
    }
}

extern "C" void kernel_launch(void* const* d_in, const int* in_sizes, int n_in,
                              void* d_out, int out_size, void* d_ws, size_t ws_size,
                              hipStream_t stream) {
    const float* cxr = (const float*)d_in[0];
    const float* ehr = (const float*)d_in[1];
    const float* temp = (const float*)d_in[2];
    float* out = (float*)d_out;

    char* ws = (char*)d_ws;
    unsigned char* Ab = (unsigned char*)ws;                        // 4 MB
    unsigned char* Bb = (unsigned char*)(ws + 4u * 1024 * 1024);   // 4 MB
    float* rs = (float*)(ws + 8u * 1024 * 1024);
    float* cs = rs + N_ROWS;
    float* dg = cs + N_ROWS;

    hipMemsetAsync(rs, 0, 2 * N_ROWS * sizeof(float), stream);
    hipMemsetAsync(out, 0, sizeof(float), stream);
    normdiag_kernel<<<dim3(N_ROWS / 4), 256, 0, stream>>>(cxr, ehr, Ab, Bb, temp, dg);
    gemm_lse_kernel<<<dim3(64 * 64), 512, 0, stream>>>(Ab, Bb, temp, rs, cs);
    finalize_kernel<<<dim3(16), 512, 0, stream>>>(rs, cs, dg, temp, out);
}